// Round 10
// baseline (270.391 us; speedup 1.0000x reference)
//
#include <hip/hip_runtime.h>

// B=8,H=8,S=1024,D=64 fp32 attention, raw-exp softmax, multiplicative key mask.
// Outputs: context[64,1024,64] then scores[64,1024,1024], both fp32.
// R10: wave = 16 q-rows x ALL 1024 keys. E kept in 128 VGPRs (fully unrolled
// loops -> static indexing, no scratch). No LDS, no barriers, no cross-wave
// combine. Per-wave flush = pure nt-store stream immediately after compute.

typedef float    f32x4 __attribute__((ext_vector_type(4)));
typedef _Float16 f16x8 __attribute__((ext_vector_type(8)));
typedef _Float16 f16x4 __attribute__((ext_vector_type(4)));

#define MFMA32(A, B, C) __builtin_amdgcn_mfma_f32_16x16x32_f16((A), (B), (C), 0, 0, 0)
#define MFMA16(A, B, C) __builtin_amdgcn_mfma_f32_16x16x16f16((A), (B), (C), 0, 0, 0)

#define BHN 64
#define SEQ 1024
#define DIM 64

__device__ inline f16x8 cvt8(f32x4 a, f32x4 b) {
    f16x8 r;
    r[0] = (_Float16)a[0]; r[1] = (_Float16)a[1]; r[2] = (_Float16)a[2]; r[3] = (_Float16)a[3];
    r[4] = (_Float16)b[0]; r[5] = (_Float16)b[1]; r[6] = (_Float16)b[2]; r[7] = (_Float16)b[3];
    return r;
}

// Pre-pass: K -> f16 same layout; V -> f16 repacked for PV:
// VTP[bh][ktg][lane][e], e=c*4+j : V[bh][ktg*16 + (lane>>4)*4 + j][c*16 + (lane&15)]
__global__ __launch_bounds__(256)
void cvt_kv(const float* __restrict__ K, const float* __restrict__ V,
            _Float16* __restrict__ Kh, _Float16* __restrict__ VTP)
{
    __shared__ _Float16 tile[128 * 65];
    const int bh = blockIdx.x >> 3;
    const int kc = blockIdx.x & 7;
    const int t  = threadIdx.x;
    const size_t base = ((size_t)bh * SEQ + (size_t)kc * 128) * DIM;

    for (int it = 0; it < 8; ++it) {
        int idx = it * 256 + t;
        int key = idx >> 4;
        int c4  = idx & 15;
        f32x4 kv = *(const f32x4*)(K + base + key * DIM + c4 * 4);
        f32x4 vv = *(const f32x4*)(V + base + key * DIM + c4 * 4);
        f16x4 kh4;
        kh4[0] = (_Float16)kv[0]; kh4[1] = (_Float16)kv[1];
        kh4[2] = (_Float16)kv[2]; kh4[3] = (_Float16)kv[3];
        *(f16x4*)(Kh + base + key * DIM + c4 * 4) = kh4;
        tile[key * 65 + c4 * 4 + 0] = (_Float16)vv[0];
        tile[key * 65 + c4 * 4 + 1] = (_Float16)vv[1];
        tile[key * 65 + c4 * 4 + 2] = (_Float16)vv[2];
        tile[key * 65 + c4 * 4 + 3] = (_Float16)vv[3];
    }
    __syncthreads();
    for (int it = 0; it < 8; ++it) {
        int flat = it * 256 + t;
        int ktl  = flat >> 8;          // 0..7
        int rem  = flat & 255;
        int l    = rem >> 2;           // lane 0..63
        int c    = rem & 3;            // dt 0..3
        f16x4 o;
        #pragma unroll
        for (int j = 0; j < 4; ++j)
            o[j] = tile[(ktl * 16 + ((l >> 4) << 2) + j) * 65 + c * 16 + (l & 15)];
        *(f16x4*)(VTP + (((size_t)bh * 64 + kc * 8 + ktl) * 64 + l) * 16 + c * 4) = o;
    }
}

// Main kernel. 1024 blocks x 256 thr (4 independent waves). Wave = 16 q-rows,
// all 1024 keys. Swapped QK^T: lane(col,g): qrow=col, keys=g*4+i per kt.
// E[kt] in VGPRs; rowsum in-register + 2 shfl; flush per wave, no sync.
template <bool PRECONV>
__global__ __launch_bounds__(256, 2)
void attn_main(const float* __restrict__ Q, const float* __restrict__ K,
               const float* __restrict__ V, const float* __restrict__ mask,
               const _Float16* __restrict__ Kh, const _Float16* __restrict__ VTP,
               float* __restrict__ ctx, float* __restrict__ scores)
{
    const int bid = blockIdx.x;
    const int wg  = ((bid & 7) << 7) | (bid >> 3);  // XCD-bijective (1024 % 8 == 0)
    const int bh  = wg >> 4;
    const int qb  = wg & 15;
    const int b   = bh >> 3;
    const int w    = threadIdx.x >> 6;
    const int lane = threadIdx.x & 63;
    const int col  = lane & 15;
    const int g    = lane >> 4;
    const int q0   = qb * 64 + w * 16;   // wave's 16 rows
    const float scale = 0.125f;

    // ---- Q fragments: Q[q0+col][f*32 + g*8 .. +7]
    f16x8 qf0, qf1;
    {
        const float* p = Q + ((size_t)bh * SEQ + q0 + col) * DIM + g * 8;
        qf0 = cvt8(*(const f32x4*)p,        *(const f32x4*)(p + 4));
        qf1 = cvt8(*(const f32x4*)(p + 32), *(const f32x4*)(p + 36));
    }
    const float* mb = mask + (size_t)b * SEQ;
    const _Float16* kbase = Kh + ((size_t)bh * SEQ + col) * DIM + g * 8;
    const _Float16* vtpb  = VTP + ((size_t)bh * 64 * 64 + lane) * 16;

    f32x4 cacc[4];
    #pragma unroll
    for (int dt = 0; dt < 4; ++dt) cacc[dt] = (f32x4){0.f, 0.f, 0.f, 0.f};

    f16x4 E[64];         // 128 VGPRs; all indices static after full unroll
    float rsum = 0.f;

    // ---- prefetch kt=0
    f16x8 k0, k1, va, vb;
    f32x4 m4;
    if (PRECONV) {
        k0 = *(const f16x8*)(kbase);
        k1 = *(const f16x8*)(kbase + 32);
        va = *(const f16x8*)(vtpb);
        vb = *(const f16x8*)(vtpb + 8);
    } else {
        const float* kp = K + ((size_t)bh * SEQ + col) * DIM + g * 8;
        k0 = cvt8(*(const f32x4*)kp,        *(const f32x4*)(kp + 4));
        k1 = cvt8(*(const f32x4*)(kp + 32), *(const f32x4*)(kp + 36));
        #pragma unroll
        for (int e = 0; e < 8; ++e) {
            va[e] = (_Float16)V[((size_t)bh * SEQ + g * 4 + (e & 3)) * DIM + (e >> 2) * 16 + col];
            vb[e] = (_Float16)V[((size_t)bh * SEQ + g * 4 + (e & 3)) * DIM + (2 + (e >> 2)) * 16 + col];
        }
    }
    m4 = *(const f32x4*)(mb + g * 4);

    #pragma unroll
    for (int kt = 0; kt < 64; ++kt) {
        const int ktn = (kt + 1) & 63;
        f16x8 n0, n1, nva, nvb;
        if (PRECONV) {
            n0  = *(const f16x8*)(kbase + (size_t)ktn * 16 * DIM);
            n1  = *(const f16x8*)(kbase + (size_t)ktn * 16 * DIM + 32);
            nva = *(const f16x8*)(vtpb + (size_t)ktn * 64 * 16);
            nvb = *(const f16x8*)(vtpb + (size_t)ktn * 64 * 16 + 8);
        } else {
            const float* kp = K + ((size_t)bh * SEQ + ktn * 16 + col) * DIM + g * 8;
            n0 = cvt8(*(const f32x4*)kp,        *(const f32x4*)(kp + 4));
            n1 = cvt8(*(const f32x4*)(kp + 32), *(const f32x4*)(kp + 36));
            #pragma unroll
            for (int e = 0; e < 8; ++e) {
                nva[e] = (_Float16)V[((size_t)bh * SEQ + ktn * 16 + g * 4 + (e & 3)) * DIM + (e >> 2) * 16 + col];
                nvb[e] = (_Float16)V[((size_t)bh * SEQ + ktn * 16 + g * 4 + (e & 3)) * DIM + (2 + (e >> 2)) * 16 + col];
            }
        }
        f32x4 nm = *(const f32x4*)(mb + ktn * 16 + g * 4);

        f32x4 acc = {0.f, 0.f, 0.f, 0.f};
        acc = MFMA32(k0, qf0, acc);
        acc = MFMA32(k1, qf1, acc);
        const float e0 = __expf(acc[0] * scale) * m4[0];
        const float e1 = __expf(acc[1] * scale) * m4[1];
        const float e2 = __expf(acc[2] * scale) * m4[2];
        const float e3 = __expf(acc[3] * scale) * m4[3];
        rsum += e0 + e1 + e2 + e3;
        f16x4 pf;
        pf[0] = (_Float16)e0; pf[1] = (_Float16)e1;
        pf[2] = (_Float16)e2; pf[3] = (_Float16)e3;
        E[kt] = pf;

        {
            f16x4 vt0 = __builtin_shufflevector(va, va, 0, 1, 2, 3);
            f16x4 vt1 = __builtin_shufflevector(va, va, 4, 5, 6, 7);
            f16x4 vt2 = __builtin_shufflevector(vb, vb, 0, 1, 2, 3);
            f16x4 vt3 = __builtin_shufflevector(vb, vb, 4, 5, 6, 7);
            cacc[0] = MFMA16(vt0, pf, cacc[0]);
            cacc[1] = MFMA16(vt1, pf, cacc[1]);
            cacc[2] = MFMA16(vt2, pf, cacc[2]);
            cacc[3] = MFMA16(vt3, pf, cacc[3]);
        }
        k0 = n0; k1 = n1; va = nva; vb = nvb; m4 = nm;
    }

    // ---- rowsum across the 4 lane-groups (same col = same q-row)
    rsum += __shfl_xor(rsum, 16, 64);
    rsum += __shfl_xor(rsum, 32, 64);
    const float inv = 1.0f / (rsum + 1e-8f);

    // ---- flush: pure nt-store stream from registers (no LDS, no barrier)
    {
        float* srow = scores + ((size_t)bh * SEQ + q0 + col) * SEQ + g * 4;
        #pragma unroll
        for (int kt = 0; kt < 64; ++kt) {
            f32x4 o;
            o[0] = (float)E[kt][0] * inv;
            o[1] = (float)E[kt][1] * inv;
            o[2] = (float)E[kt][2] * inv;
            o[3] = (float)E[kt][3] * inv;
            __builtin_nontemporal_store(o, (f32x4*)(srow + kt * 16));
        }
    }

    // ---- ctx: complete per-wave (saw all keys); lane(col,g) holds
    // ctx[q0+col][dt*16 + g*4 .. +3]
    #pragma unroll
    for (int dt = 0; dt < 4; ++dt) {
        f32x4 r = cacc[dt];
        r[0] *= inv; r[1] *= inv; r[2] *= inv; r[3] *= inv;
        *(f32x4*)(ctx + ((size_t)bh * SEQ + q0 + col) * DIM + dt * 16 + g * 4) = r;
    }
}

extern "C" void kernel_launch(void* const* d_in, const int* in_sizes, int n_in,
                              void* d_out, int out_size, void* d_ws, size_t ws_size,
                              hipStream_t stream)
{
    const float* Q    = (const float*)d_in[0];
    const float* K    = (const float*)d_in[1];
    const float* V    = (const float*)d_in[2];
    const float* mask = (const float*)d_in[3];
    float* ctx    = (float*)d_out;
    float* scores = ctx + (size_t)BHN * SEQ * DIM;

    const size_t elems = (size_t)BHN * SEQ * DIM;       // 4,194,304
    const size_t need  = elems * 2 * sizeof(_Float16);  // Kh + VTP = 16 MB
    if (ws_size >= need) {
        _Float16* Kh  = (_Float16*)d_ws;
        _Float16* VTP = Kh + elems;
        cvt_kv<<<512, 256, 0, stream>>>(K, V, Kh, VTP);
        attn_main<true><<<1024, 256, 0, stream>>>(Q, K, V, mask, Kh, VTP, ctx, scores);
    } else {
        attn_main<false><<<1024, 256, 0, stream>>>(Q, K, V, mask, nullptr, nullptr, ctx, scores);
    }
}

// Round 11
// 145.880 us; speedup vs baseline: 1.8535x; 1.8535x over previous
//
#include <hip/hip_runtime.h>

// B=8,H=8,S=1024,D=64 fp32 attention, raw-exp softmax, multiplicative key mask.
// Outputs: context[64,1024,64] then scores[64,1024,1024], both fp32.
// R11: E in REGISTERS, spill-proof sizing. Wave = 16 q-rows x 512 keys ->
// E[32] f16x4 = 64 VGPR (R10's E[64]=128 VGPR spilled; FETCH showed 140 MB
// scratch traffic). Rowsum via partner-wave LDS exchange; ctx combine via
// 8 KB LDS; flush = per-wave nt-store stream, LAST, with no trailing barrier.

typedef float    f32x4 __attribute__((ext_vector_type(4)));
typedef _Float16 f16x8 __attribute__((ext_vector_type(8)));
typedef _Float16 f16x4 __attribute__((ext_vector_type(4)));

#define MFMA32(A, B, C) __builtin_amdgcn_mfma_f32_16x16x32_f16((A), (B), (C), 0, 0, 0)
#define MFMA16(A, B, C) __builtin_amdgcn_mfma_f32_16x16x16f16((A), (B), (C), 0, 0, 0)

#define BHN 64
#define SEQ 1024
#define DIM 64

__device__ inline f16x8 cvt8(f32x4 a, f32x4 b) {
    f16x8 r;
    r[0] = (_Float16)a[0]; r[1] = (_Float16)a[1]; r[2] = (_Float16)a[2]; r[3] = (_Float16)a[3];
    r[4] = (_Float16)b[0]; r[5] = (_Float16)b[1]; r[6] = (_Float16)b[2]; r[7] = (_Float16)b[3];
    return r;
}

// Pre-pass: K -> f16 same layout; V -> f16 repacked for PV:
// VTP[bh][ktg][lane][e], e=c*4+j : V[bh][ktg*16 + (lane>>4)*4 + j][c*16 + (lane&15)]
__global__ __launch_bounds__(256)
void cvt_kv(const float* __restrict__ K, const float* __restrict__ V,
            _Float16* __restrict__ Kh, _Float16* __restrict__ VTP)
{
    __shared__ _Float16 tile[128 * 65];
    const int bh = blockIdx.x >> 3;
    const int kc = blockIdx.x & 7;
    const int t  = threadIdx.x;
    const size_t base = ((size_t)bh * SEQ + (size_t)kc * 128) * DIM;

    for (int it = 0; it < 8; ++it) {
        int idx = it * 256 + t;
        int key = idx >> 4;
        int c4  = idx & 15;
        f32x4 kv = *(const f32x4*)(K + base + key * DIM + c4 * 4);
        f32x4 vv = *(const f32x4*)(V + base + key * DIM + c4 * 4);
        f16x4 kh4;
        kh4[0] = (_Float16)kv[0]; kh4[1] = (_Float16)kv[1];
        kh4[2] = (_Float16)kv[2]; kh4[3] = (_Float16)kv[3];
        *(f16x4*)(Kh + base + key * DIM + c4 * 4) = kh4;
        tile[key * 65 + c4 * 4 + 0] = (_Float16)vv[0];
        tile[key * 65 + c4 * 4 + 1] = (_Float16)vv[1];
        tile[key * 65 + c4 * 4 + 2] = (_Float16)vv[2];
        tile[key * 65 + c4 * 4 + 3] = (_Float16)vv[3];
    }
    __syncthreads();
    for (int it = 0; it < 8; ++it) {
        int flat = it * 256 + t;
        int ktl  = flat >> 8;          // 0..7
        int rem  = flat & 255;
        int l    = rem >> 2;           // lane 0..63
        int c    = rem & 3;            // dt 0..3
        f16x4 o;
        #pragma unroll
        for (int j = 0; j < 4; ++j)
            o[j] = tile[(ktl * 16 + ((l >> 4) << 2) + j) * 65 + c * 16 + (l & 15)];
        *(f16x4*)(VTP + (((size_t)bh * 64 + kc * 8 + ktl) * 64 + l) * 16 + c * 4) = o;
    }
}

// Main kernel. 2048 blocks x 256 thr (4 waves). Block = 32 q-rows of one (b,h).
// Wave (pq = w>>1, khf = w&1): rows q0+pq*16 (row = lane&15), keys khf*512 +
// kt*16 + (lane>>4)*4+i, kt = 0..31. Swapped QK^T; E[32] f16x4 in VGPRs.
template <bool PRECONV>
__global__ __launch_bounds__(256, 2)
void attn_main(const float* __restrict__ Q, const float* __restrict__ K,
               const float* __restrict__ V, const float* __restrict__ mask,
               const _Float16* __restrict__ Kh, const _Float16* __restrict__ VTP,
               float* __restrict__ ctx, float* __restrict__ scores)
{
    __shared__ float rs[2][2][16];        // rowsum partials
    __shared__ float cbuf[2][16][64];     // 8 KB ctx combine

    const int bid = blockIdx.x;
    const int wg  = ((bid & 7) << 8) | (bid >> 3);  // XCD-bijective (2048 % 8 == 0)
    const int bh  = wg >> 5;
    const int qb  = wg & 31;
    const int b   = bh >> 3;
    const int w    = threadIdx.x >> 6;
    const int lane = threadIdx.x & 63;
    const int col  = lane & 15;
    const int g    = lane >> 4;
    const int pq   = w >> 1;
    const int khf  = w & 1;
    const int q0   = qb * 32;
    const int kb   = khf * 512;
    const float scale = 0.125f;

    // ---- Q fragments: Q[q0+pq*16+col][f*32 + g*8 .. +7]
    f16x8 qf0, qf1;
    {
        const float* p = Q + ((size_t)bh * SEQ + q0 + pq * 16 + col) * DIM + g * 8;
        qf0 = cvt8(*(const f32x4*)p,        *(const f32x4*)(p + 4));
        qf1 = cvt8(*(const f32x4*)(p + 32), *(const f32x4*)(p + 36));
    }
    const float* mb = mask + (size_t)b * SEQ + kb;
    const _Float16* kbase = Kh + ((size_t)bh * SEQ + kb + col) * DIM + g * 8;
    const _Float16* vtpb  = VTP + (((size_t)bh * 64 + khf * 32) * 64 + lane) * 16;

    f32x4 cacc[4];
    #pragma unroll
    for (int dt = 0; dt < 4; ++dt) cacc[dt] = (f32x4){0.f, 0.f, 0.f, 0.f};

    f16x4 E[32];     // 64 VGPRs; static indices via full unroll
    float rsum = 0.f;

    // ---- prefetch kt=0
    f16x8 k0, k1, va, vb;
    f32x4 m4;
    if (PRECONV) {
        k0 = *(const f16x8*)(kbase);
        k1 = *(const f16x8*)(kbase + 32);
        va = *(const f16x8*)(vtpb);
        vb = *(const f16x8*)(vtpb + 8);
    } else {
        const float* kp = K + ((size_t)bh * SEQ + kb + col) * DIM + g * 8;
        k0 = cvt8(*(const f32x4*)kp,        *(const f32x4*)(kp + 4));
        k1 = cvt8(*(const f32x4*)(kp + 32), *(const f32x4*)(kp + 36));
        #pragma unroll
        for (int e = 0; e < 8; ++e) {
            va[e] = (_Float16)V[((size_t)bh * SEQ + kb + g * 4 + (e & 3)) * DIM + (e >> 2) * 16 + col];
            vb[e] = (_Float16)V[((size_t)bh * SEQ + kb + g * 4 + (e & 3)) * DIM + (2 + (e >> 2)) * 16 + col];
        }
    }
    m4 = *(const f32x4*)(mb + g * 4);

    #pragma unroll
    for (int kt = 0; kt < 32; ++kt) {
        const int ktn = (kt + 1) & 31;
        f16x8 n0, n1, nva, nvb;
        if (PRECONV) {
            n0  = *(const f16x8*)(kbase + (size_t)ktn * 16 * DIM);
            n1  = *(const f16x8*)(kbase + (size_t)ktn * 16 * DIM + 32);
            nva = *(const f16x8*)(vtpb + (size_t)ktn * 64 * 16);
            nvb = *(const f16x8*)(vtpb + (size_t)ktn * 64 * 16 + 8);
        } else {
            const float* kp = K + ((size_t)bh * SEQ + kb + ktn * 16 + col) * DIM + g * 8;
            n0 = cvt8(*(const f32x4*)kp,        *(const f32x4*)(kp + 4));
            n1 = cvt8(*(const f32x4*)(kp + 32), *(const f32x4*)(kp + 36));
            #pragma unroll
            for (int e = 0; e < 8; ++e) {
                nva[e] = (_Float16)V[((size_t)bh * SEQ + kb + ktn * 16 + g * 4 + (e & 3)) * DIM + (e >> 2) * 16 + col];
                nvb[e] = (_Float16)V[((size_t)bh * SEQ + kb + ktn * 16 + g * 4 + (e & 3)) * DIM + (2 + (e >> 2)) * 16 + col];
            }
        }
        f32x4 nm = *(const f32x4*)(mb + ktn * 16 + g * 4);

        f32x4 acc = {0.f, 0.f, 0.f, 0.f};
        acc = MFMA32(k0, qf0, acc);
        acc = MFMA32(k1, qf1, acc);
        const float e0 = __expf(acc[0] * scale) * m4[0];
        const float e1 = __expf(acc[1] * scale) * m4[1];
        const float e2 = __expf(acc[2] * scale) * m4[2];
        const float e3 = __expf(acc[3] * scale) * m4[3];
        rsum += e0 + e1 + e2 + e3;
        f16x4 pf;
        pf[0] = (_Float16)e0; pf[1] = (_Float16)e1;
        pf[2] = (_Float16)e2; pf[3] = (_Float16)e3;
        E[kt] = pf;

        {
            f16x4 vt0 = __builtin_shufflevector(va, va, 0, 1, 2, 3);
            f16x4 vt1 = __builtin_shufflevector(va, va, 4, 5, 6, 7);
            f16x4 vt2 = __builtin_shufflevector(vb, vb, 0, 1, 2, 3);
            f16x4 vt3 = __builtin_shufflevector(vb, vb, 4, 5, 6, 7);
            cacc[0] = MFMA16(vt0, pf, cacc[0]);
            cacc[1] = MFMA16(vt1, pf, cacc[1]);
            cacc[2] = MFMA16(vt2, pf, cacc[2]);
            cacc[3] = MFMA16(vt3, pf, cacc[3]);
        }
        k0 = n0; k1 = n1; va = nva; vb = nvb; m4 = nm;
    }

    // ---- rowsum: reduce lane-groups, exchange with partner key-half wave
    rsum += __shfl_xor(rsum, 16, 64);
    rsum += __shfl_xor(rsum, 32, 64);
    if (g == 0) rs[pq][khf][col] = rsum;
    __syncthreads();
    const float inv = 1.0f / (rs[pq][0][col] + rs[pq][1][col] + 1e-8f);

    // ---- ctx combine across key-halves (fast), then flush (slow, unsynced)
    #pragma unroll
    for (int dt = 0; dt < 4; ++dt) {
        cacc[dt][0] *= inv; cacc[dt][1] *= inv;
        cacc[dt][2] *= inv; cacc[dt][3] *= inv;
    }
    if (khf == 1) {
        #pragma unroll
        for (int dt = 0; dt < 4; ++dt)
            #pragma unroll
            for (int i = 0; i < 4; ++i)
                cbuf[pq][dt * 4 + i][lane] = cacc[dt][i];
    }
    __syncthreads();
    if (khf == 0) {
        #pragma unroll
        for (int dt = 0; dt < 4; ++dt) {
            f32x4 r = cacc[dt];
            #pragma unroll
            for (int i = 0; i < 4; ++i) r[i] += cbuf[pq][dt * 4 + i][lane];
            *(f32x4*)(ctx + ((size_t)bh * SEQ + q0 + pq * 16 + col) * DIM + dt * 16 + g * 4) = r;
        }
    }

    // ---- flush: per-wave nt-store stream from registers, no trailing barrier
    {
        float* srow = scores + ((size_t)bh * SEQ + q0 + pq * 16 + col) * SEQ + kb + g * 4;
        #pragma unroll
        for (int kt = 0; kt < 32; ++kt) {
            f32x4 o;
            o[0] = (float)E[kt][0] * inv;
            o[1] = (float)E[kt][1] * inv;
            o[2] = (float)E[kt][2] * inv;
            o[3] = (float)E[kt][3] * inv;
            __builtin_nontemporal_store(o, (f32x4*)(srow + kt * 16));
        }
    }
}

extern "C" void kernel_launch(void* const* d_in, const int* in_sizes, int n_in,
                              void* d_out, int out_size, void* d_ws, size_t ws_size,
                              hipStream_t stream)
{
    const float* Q    = (const float*)d_in[0];
    const float* K    = (const float*)d_in[1];
    const float* V    = (const float*)d_in[2];
    const float* mask = (const float*)d_in[3];
    float* ctx    = (float*)d_out;
    float* scores = ctx + (size_t)BHN * SEQ * DIM;

    const size_t elems = (size_t)BHN * SEQ * DIM;       // 4,194,304
    const size_t need  = elems * 2 * sizeof(_Float16);  // Kh + VTP = 16 MB
    if (ws_size >= need) {
        _Float16* Kh  = (_Float16*)d_ws;
        _Float16* VTP = Kh + elems;
        cvt_kv<<<512, 256, 0, stream>>>(K, V, Kh, VTP);
        attn_main<true><<<2048, 256, 0, stream>>>(Q, K, V, mask, Kh, VTP, ctx, scores);
    } else {
        attn_main<false><<<2048, 256, 0, stream>>>(Q, K, V, mask, nullptr, nullptr, ctx, scores);
    }
}

// Round 12
// 111.252 us; speedup vs baseline: 2.4304x; 1.3113x over previous
//
#include <hip/hip_runtime.h>

// B=8,H=8,S=1024,D=64 fp32 attention, raw-exp softmax, multiplicative key mask.
// Outputs: context[64,1024,64] then scores[64,1024,1024], both fp32.
// R12 = R9 (best: 101 us) with ONE change: flush stores are plain cached
// stores instead of nontemporal. Rationale: R4-vs-R6's nt win predates the
// prefetch; with latency covered, routing the 268 MB scores stream through
// L2 may regain fill-level write BW (6.9 vs ~4.9 TB/s).
// (R11 lesson kept: flush must stay LDS-staged so wave store footprints are
// full cache lines; register-direct 64-B-segment nt scatter cost +45 us.)

typedef float    f32x4 __attribute__((ext_vector_type(4)));
typedef _Float16 f16x8 __attribute__((ext_vector_type(8)));
typedef _Float16 f16x4 __attribute__((ext_vector_type(4)));

#define MFMA32(A, B, C) __builtin_amdgcn_mfma_f32_16x16x32_f16((A), (B), (C), 0, 0, 0)
#define MFMA16(A, B, C) __builtin_amdgcn_mfma_f32_16x16x16f16((A), (B), (C), 0, 0, 0)

#define BHN 64
#define SEQ 1024
#define DIM 64

__device__ inline f16x8 cvt8(f32x4 a, f32x4 b) {
    f16x8 r;
    r[0] = (_Float16)a[0]; r[1] = (_Float16)a[1]; r[2] = (_Float16)a[2]; r[3] = (_Float16)a[3];
    r[4] = (_Float16)b[0]; r[5] = (_Float16)b[1]; r[6] = (_Float16)b[2]; r[7] = (_Float16)b[3];
    return r;
}

// Pre-pass: K -> f16 same layout; V -> f16 repacked for PV:
// VTP[bh][ktg][lane][e], e=c*4+j : V[bh][ktg*16 + (lane>>4)*4 + j][c*16 + (lane&15)]
__global__ __launch_bounds__(256)
void cvt_kv(const float* __restrict__ K, const float* __restrict__ V,
            _Float16* __restrict__ Kh, _Float16* __restrict__ VTP)
{
    __shared__ _Float16 tile[128 * 65];
    const int bh = blockIdx.x >> 3;
    const int kc = blockIdx.x & 7;
    const int t  = threadIdx.x;
    const size_t base = ((size_t)bh * SEQ + (size_t)kc * 128) * DIM;

    for (int it = 0; it < 8; ++it) {
        int idx = it * 256 + t;
        int key = idx >> 4;
        int c4  = idx & 15;
        f32x4 kv = *(const f32x4*)(K + base + key * DIM + c4 * 4);
        f32x4 vv = *(const f32x4*)(V + base + key * DIM + c4 * 4);
        f16x4 kh4;
        kh4[0] = (_Float16)kv[0]; kh4[1] = (_Float16)kv[1];
        kh4[2] = (_Float16)kv[2]; kh4[3] = (_Float16)kv[3];
        *(f16x4*)(Kh + base + key * DIM + c4 * 4) = kh4;
        tile[key * 65 + c4 * 4 + 0] = (_Float16)vv[0];
        tile[key * 65 + c4 * 4 + 1] = (_Float16)vv[1];
        tile[key * 65 + c4 * 4 + 2] = (_Float16)vv[2];
        tile[key * 65 + c4 * 4 + 3] = (_Float16)vv[3];
    }
    __syncthreads();
    for (int it = 0; it < 8; ++it) {
        int flat = it * 256 + t;
        int ktl  = flat >> 8;          // 0..7
        int rem  = flat & 255;
        int l    = rem >> 2;           // lane 0..63
        int c    = rem & 3;            // dt 0..3
        f16x4 o;
        #pragma unroll
        for (int j = 0; j < 4; ++j)
            o[j] = tile[(ktl * 16 + ((l >> 4) << 2) + j) * 65 + c * 16 + (l & 15)];
        *(f16x4*)(VTP + (((size_t)bh * 64 + kc * 8 + ktl) * 64 + l) * 16 + c * 4) = o;
    }
}

// Main kernel. 2048 blocks x 256 thr. Block = 32 q-rows of one (b,h), all keys.
// Wave w owns key quarter [w*256, ...). Swapped QK^T: lane qrow = lane&15,
// keys = (lane>>4)*4+i. E staged f16 in 64 KB LDS (XOR-swizzled granules),
// flush phase: contiguous 1-KB row stores. Epilogue: PV combine via LDS.
template <bool PRECONV>
__global__ __launch_bounds__(256, 2)
void attn_main(const float* __restrict__ Q, const float* __restrict__ K,
               const float* __restrict__ V, const float* __restrict__ mask,
               const _Float16* __restrict__ Kh, const _Float16* __restrict__ VTP,
               float* __restrict__ ctx, float* __restrict__ scores)
{
    __shared__ _Float16 Et[32 * 1024];   // 64 KB

    const int bid = blockIdx.x;
    const int wg  = ((bid & 7) << 8) | (bid >> 3);  // XCD-bijective (2048 % 8 == 0)
    const int bh  = wg >> 5;
    const int qb  = wg & 31;
    const int b   = bh >> 3;
    const int w    = threadIdx.x >> 6;   // key quarter
    const int lane = threadIdx.x & 63;
    const int col  = lane & 15;
    const int g    = lane >> 4;
    const int q0   = qb * 32;
    const int kb   = w * 256;
    const float scale = 0.125f;
    char* EtB = (char*)Et;

    // ---- Q fragments: qf[s][f] : Q[q0+s*16+col][f*32 + g*8 .. +7]
    f16x8 qf[2][2];
    {
        const float* qbase = Q + ((size_t)bh * SEQ + q0) * DIM;
        #pragma unroll
        for (int s = 0; s < 2; ++s)
            #pragma unroll
            for (int f = 0; f < 2; ++f) {
                const float* p = qbase + (s * 16 + col) * DIM + f * 32 + g * 8;
                qf[s][f] = cvt8(*(const f32x4*)p, *(const f32x4*)(p + 4));
            }
    }
    const float* mb = mask + (size_t)b * SEQ + kb;
    const _Float16* kbase = Kh + ((size_t)bh * SEQ + kb + col) * DIM + g * 8;
    const _Float16* vtpb  = VTP + (((size_t)bh * 64 + w * 16) * 64 + lane) * 16;

    f32x4 cacc[2][4];
    #pragma unroll
    for (int s = 0; s < 2; ++s)
        #pragma unroll
        for (int dt = 0; dt < 4; ++dt) cacc[s][dt] = (f32x4){0.f, 0.f, 0.f, 0.f};

    // ---- single pass, one-ahead prefetch of all 5 loads
    f16x8 k0, k1, va, vb;
    f32x4 m4;
    if (PRECONV) {
        k0 = *(const f16x8*)(kbase);
        k1 = *(const f16x8*)(kbase + 32);
        va = *(const f16x8*)(vtpb);
        vb = *(const f16x8*)(vtpb + 8);
    } else {
        const float* kp = K + ((size_t)bh * SEQ + kb + col) * DIM + g * 8;
        k0 = cvt8(*(const f32x4*)kp,        *(const f32x4*)(kp + 4));
        k1 = cvt8(*(const f32x4*)(kp + 32), *(const f32x4*)(kp + 36));
        #pragma unroll
        for (int e = 0; e < 8; ++e) {
            va[e] = (_Float16)V[((size_t)bh * SEQ + kb + g * 4 + (e & 3)) * DIM + (e >> 2) * 16 + col];
            vb[e] = (_Float16)V[((size_t)bh * SEQ + kb + g * 4 + (e & 3)) * DIM + (2 + (e >> 2)) * 16 + col];
        }
    }
    m4 = *(const f32x4*)(mb + g * 4);

    for (int kt = 0; kt < 16; ++kt) {
        const int ktn = (kt + 1) & 15;
        f16x8 n0, n1, nva, nvb;
        if (PRECONV) {
            n0  = *(const f16x8*)(kbase + (size_t)ktn * 16 * DIM);
            n1  = *(const f16x8*)(kbase + (size_t)ktn * 16 * DIM + 32);
            nva = *(const f16x8*)(vtpb + (size_t)ktn * 64 * 16);
            nvb = *(const f16x8*)(vtpb + (size_t)ktn * 64 * 16 + 8);
        } else {
            const float* kp = K + ((size_t)bh * SEQ + kb + ktn * 16 + col) * DIM + g * 8;
            n0 = cvt8(*(const f32x4*)kp,        *(const f32x4*)(kp + 4));
            n1 = cvt8(*(const f32x4*)(kp + 32), *(const f32x4*)(kp + 36));
            #pragma unroll
            for (int e = 0; e < 8; ++e) {
                nva[e] = (_Float16)V[((size_t)bh * SEQ + kb + ktn * 16 + g * 4 + (e & 3)) * DIM + (e >> 2) * 16 + col];
                nvb[e] = (_Float16)V[((size_t)bh * SEQ + kb + ktn * 16 + g * 4 + (e & 3)) * DIM + (2 + (e >> 2)) * 16 + col];
            }
        }
        f32x4 nm = *(const f32x4*)(mb + ktn * 16 + g * 4);

        f16x4 pf[2];
        #pragma unroll
        for (int s = 0; s < 2; ++s) {
            f32x4 acc = {0.f, 0.f, 0.f, 0.f};
            acc = MFMA32(k0, qf[s][0], acc);
            acc = MFMA32(k1, qf[s][1], acc);
            f16x4 eh;
            eh[0] = (_Float16)(__expf(acc[0] * scale) * m4[0]);
            eh[1] = (_Float16)(__expf(acc[1] * scale) * m4[1]);
            eh[2] = (_Float16)(__expf(acc[2] * scale) * m4[2]);
            eh[3] = (_Float16)(__expf(acc[3] * scale) * m4[3]);
            pf[s] = eh;
            const int row = s * 16 + col;
            const int kg  = (w * 64 + kt * 4 + g) ^ ((row & 3) << 2);
            *(f16x4*)(EtB + row * 2048 + kg * 8) = eh;
        }
        {
            f16x4 vt0 = __builtin_shufflevector(va, va, 0, 1, 2, 3);
            f16x4 vt1 = __builtin_shufflevector(va, va, 4, 5, 6, 7);
            f16x4 vt2 = __builtin_shufflevector(vb, vb, 0, 1, 2, 3);
            f16x4 vt3 = __builtin_shufflevector(vb, vb, 4, 5, 6, 7);
            cacc[0][0] = MFMA16(vt0, pf[0], cacc[0][0]);
            cacc[1][0] = MFMA16(vt0, pf[1], cacc[1][0]);
            cacc[0][1] = MFMA16(vt1, pf[0], cacc[0][1]);
            cacc[1][1] = MFMA16(vt1, pf[1], cacc[1][1]);
            cacc[0][2] = MFMA16(vt2, pf[0], cacc[0][2]);
            cacc[1][2] = MFMA16(vt2, pf[1], cacc[1][2]);
            cacc[0][3] = MFMA16(vt3, pf[0], cacc[0][3]);
            cacc[1][3] = MFMA16(vt3, pf[1], cacc[1][3]);
        }
        k0 = n0; k1 = n1; va = nva; vb = nvb; m4 = nm;
    }

    __syncthreads();

    // ---- flush phase: wave w rows w*8..w*8+7; rowsum from tile, scale,
    // contiguous 1-KB wave stores. R12: PLAIN cached stores (was nt in R9).
    const int r0 = w * 8;
    float* srow = scores + ((size_t)bh * SEQ + q0) * SEQ;
    for (int j = 0; j < 8; ++j) {
        const int r = r0 + j;
        f16x4 ev[4];
        #pragma unroll
        for (int q = 0; q < 4; ++q) {
            const int kg = (q * 64 + lane) ^ ((r & 3) << 2);
            ev[q] = *(const f16x4*)(EtB + r * 2048 + kg * 8);
        }
        float s0 = 0.f;
        #pragma unroll
        for (int q = 0; q < 4; ++q)
            #pragma unroll
            for (int i = 0; i < 4; ++i) s0 += (float)ev[q][i];
        #pragma unroll
        for (int off = 1; off < 64; off <<= 1) s0 += __shfl_xor(s0, off, 64);
        const float invr = 1.0f / (s0 + 1e-8f);
        float* dst = srow + (size_t)r * SEQ + lane * 4;
        #pragma unroll
        for (int q = 0; q < 4; ++q) {
            f32x4 o;
            o[0] = (float)ev[q][0] * invr;
            o[1] = (float)ev[q][1] * invr;
            o[2] = (float)ev[q][2] * invr;
            o[3] = (float)ev[q][3] * invr;
            *(f32x4*)(dst + q * 256) = o;   // R12: plain cached store
        }
        if (lane == 0) *(float*)(EtB + r0 * 2048 + j * 4) = invr;
    }

    __syncthreads();

    // ---- PV combine epilogue (unchanged)
    if (w != 0) {
        float* dump = (float*)(EtB + (1 + (w - 1) * 8) * 2048);
        #pragma unroll
        for (int s = 0; s < 2; ++s)
            #pragma unroll
            for (int dt = 0; dt < 4; ++dt)
                #pragma unroll
                for (int i = 0; i < 4; ++i)
                    dump[((s * 4 + dt) * 4 + i) * 64 + lane] = cacc[s][dt][i];
    }
    __syncthreads();
    if (w == 0) {
        #pragma unroll
        for (int s = 0; s < 2; ++s) {
            const int qrow = s * 16 + col;
            const float invr = *(const float*)(EtB + (qrow >> 3) * 8 * 2048 + (qrow & 7) * 4);
            #pragma unroll
            for (int dt = 0; dt < 4; ++dt) {
                f32x4 r = cacc[s][dt];
                #pragma unroll
                for (int ww = 1; ww < 4; ++ww) {
                    const float* dump = (const float*)(EtB + (1 + (ww - 1) * 8) * 2048);
                    #pragma unroll
                    for (int i = 0; i < 4; ++i)
                        r[i] += dump[((s * 4 + dt) * 4 + i) * 64 + lane];
                }
                r[0] *= invr; r[1] *= invr; r[2] *= invr; r[3] *= invr;
                *(f32x4*)(ctx + ((size_t)bh * SEQ + q0 + qrow) * DIM + dt * 16 + g * 4) = r;
            }
        }
    }
}

extern "C" void kernel_launch(void* const* d_in, const int* in_sizes, int n_in,
                              void* d_out, int out_size, void* d_ws, size_t ws_size,
                              hipStream_t stream)
{
    const float* Q    = (const float*)d_in[0];
    const float* K    = (const float*)d_in[1];
    const float* V    = (const float*)d_in[2];
    const float* mask = (const float*)d_in[3];
    float* ctx    = (float*)d_out;
    float* scores = ctx + (size_t)BHN * SEQ * DIM;

    const size_t elems = (size_t)BHN * SEQ * DIM;       // 4,194,304
    const size_t need  = elems * 2 * sizeof(_Float16);  // Kh + VTP = 16 MB
    if (ws_size >= need) {
        _Float16* Kh  = (_Float16*)d_ws;
        _Float16* VTP = Kh + elems;
        cvt_kv<<<512, 256, 0, stream>>>(K, V, Kh, VTP);
        attn_main<true><<<2048, 256, 0, stream>>>(Q, K, V, mask, Kh, VTP, ctx, scores);
    } else {
        attn_main<false><<<2048, 256, 0, stream>>>(Q, K, V, mask, nullptr, nullptr, ctx, scores);
    }
}